// Round 4
// baseline (282.086 us; speedup 1.0000x reference)
//
#include <hip/hip_runtime.h>

namespace {

constexpr int B_ = 256, C_ = 3, H_ = 224, W_ = 224;
constexpr int HW   = H_ * W_;     // 50176
constexpr int HW4  = HW / 4;      // 12544 float4 groups per plane
constexpr int W4   = W_ / 4;      // 56 float4 groups per row
constexpr int BLK  = 256;
constexpr int BLOCKS_PER_IMG = HW4 / BLK;  // 49 (exact)
constexpr int NPLANES = B_ * C_;           // 768

using f4 = __attribute__((ext_vector_type(4))) float;

__device__ __forceinline__ f4 rev4(f4 v) {
    f4 r; r.x = v.w; r.y = v.z; r.z = v.y; r.w = v.x; return r;
}
__device__ __forceinline__ float clip1(float v) {
    return fminf(fmaxf(v, -2.5f), 2.5f);
}

// Shared transform body. ApplyContrast is compile-time: the nc path never
// touches `means`. A = brightness*(cf or 1), Bc = br*(1-cf)*mean_eff or 0.
template <bool ApplyContrast>
__device__ __forceinline__ void xform_tile(
    const float* __restrict__ x, float* __restrict__ out,
    int b, int p,
    const float* __restrict__ brightness, const float* __restrict__ cfac,
    const int* __restrict__ flip_mask, const int* __restrict__ gray_mask,
    const float* __restrict__ means) {

    const int h  = p / W4;
    const int w4 = p % W4;

    const bool fl = flip_mask[b] != 0;
    const bool gr = gray_mask[b] != 0;
    const float br = brightness[b];

    float A = br;
    float B0 = 0.f, B1 = 0.f, B2 = 0.f;
    if constexpr (ApplyContrast) {
        const float cf = cfac[b];
        const float m0 = means[b * 3 + 0];
        const float m1 = means[b * 3 + 1];
        const float m2 = means[b * 3 + 2];
        A = br * cf;
        const float k = br * (1.f - cf);
        if (gr) {
            const float gm = 0.2989f * m0 + 0.587f * m1 + 0.114f * m2;
            B0 = B1 = B2 = k * gm;
        } else {
            B0 = k * m0; B1 = k * m1; B2 = k * m2;
        }
    }

    const int srcw4 = fl ? (W4 - 1 - w4) : w4;
    const size_t src = (size_t)b * (C_ * HW) + (size_t)h * W_ + (size_t)srcw4 * 4;

    f4 r  = __builtin_nontemporal_load(reinterpret_cast<const f4*>(x + src));
    f4 g  = __builtin_nontemporal_load(reinterpret_cast<const f4*>(x + src + HW));
    f4 bl = __builtin_nontemporal_load(reinterpret_cast<const f4*>(x + src + 2 * HW));
    if (fl) { r = rev4(r); g = rev4(g); bl = rev4(bl); }

    if (gr) {
        f4 gy;
        gy.x = 0.2989f * r.x + 0.587f * g.x + 0.114f * bl.x;
        gy.y = 0.2989f * r.y + 0.587f * g.y + 0.114f * bl.y;
        gy.z = 0.2989f * r.z + 0.587f * g.z + 0.114f * bl.z;
        gy.w = 0.2989f * r.w + 0.587f * g.w + 0.114f * bl.w;
        r = gy; g = gy; bl = gy;
    }

    f4 o0, o1, o2;
    o0.x = clip1(r.x * A + B0);  o0.y = clip1(r.y * A + B0);
    o0.z = clip1(r.z * A + B0);  o0.w = clip1(r.w * A + B0);
    o1.x = clip1(g.x * A + B1);  o1.y = clip1(g.y * A + B1);
    o1.z = clip1(g.z * A + B1);  o1.w = clip1(g.w * A + B1);
    o2.x = clip1(bl.x * A + B2); o2.y = clip1(bl.y * A + B2);
    o2.z = clip1(bl.z * A + B2); o2.w = clip1(bl.w * A + B2);

    const size_t dst = (size_t)b * (C_ * HW) + (size_t)h * W_ + (size_t)w4 * 4;
    __builtin_nontemporal_store(o0, reinterpret_cast<f4*>(out + dst));
    __builtin_nontemporal_store(o1, reinterpret_cast<f4*>(out + dst + HW));
    __builtin_nontemporal_store(o2, reinterpret_cast<f4*>(out + dst + 2 * HW));
}

// ---------------------------------------------------------------------------
// Kernel A (fused): blocks [0,768) = per-plane means for contrast images
// (cached loads → planes land in L3 for kernel B); blocks [768,...) =
// transform for NON-contrast images (independent of the means).
// ---------------------------------------------------------------------------
__global__ __launch_bounds__(BLK) void fusedA_kernel(
    const float* __restrict__ x,
    const float* __restrict__ brightness,
    const int*  __restrict__ flip_mask,
    const int*  __restrict__ gray_mask,
    const int*  __restrict__ contrast_apply,
    float* __restrict__ means,
    float* __restrict__ out) {

    if (blockIdx.x < NPLANES) {
        const int plane = blockIdx.x;
        if (contrast_apply[plane / 3] == 0) {
            if (threadIdx.x == 0) means[plane] = 0.f;  // hygiene
            return;
        }
        const f4* p = reinterpret_cast<const f4*>(x) + (size_t)plane * HW4;
        float s = 0.f;
#pragma unroll 4
        for (int i = threadIdx.x; i < HW4; i += BLK) {
            f4 v = p[i];
            s += (v.x + v.y) + (v.z + v.w);
        }
#pragma unroll
        for (int off = 32; off > 0; off >>= 1) s += __shfl_down(s, off, 64);

        __shared__ float partial[BLK / 64];
        if ((threadIdx.x & 63) == 0) partial[threadIdx.x >> 6] = s;
        __syncthreads();
        if (threadIdx.x == 0) {
            float t = (partial[0] + partial[1]) + (partial[2] + partial[3]);
            means[plane] = t * (1.0f / HW);
        }
        return;
    }

    const int idx = blockIdx.x - NPLANES;
    const int b = idx / BLOCKS_PER_IMG;
    if (contrast_apply[b] != 0) return;  // contrast images handled by kernel B
    const int p = (idx % BLOCKS_PER_IMG) * BLK + threadIdx.x;
    xform_tile<false>(x, out, b, p, brightness, nullptr, flip_mask, gray_mask,
                      nullptr);
}

// ---------------------------------------------------------------------------
// Kernel B: transform for contrast images only (x-reads mostly L3 hits).
// ---------------------------------------------------------------------------
__global__ __launch_bounds__(BLK) void xformC_kernel(
    const float* __restrict__ x,
    const float* __restrict__ brightness,
    const float* __restrict__ cfac,
    const int*  __restrict__ flip_mask,
    const int*  __restrict__ gray_mask,
    const int*  __restrict__ contrast_apply,
    const float* __restrict__ means,
    float* __restrict__ out) {

    const int b = blockIdx.x / BLOCKS_PER_IMG;
    if (contrast_apply[b] == 0) return;  // handled in kernel A
    const int p = (blockIdx.x % BLOCKS_PER_IMG) * BLK + threadIdx.x;
    xform_tile<true>(x, out, b, p, brightness, cfac, flip_mask, gray_mask,
                     means);
}

}  // namespace

extern "C" void kernel_launch(void* const* d_in, const int* in_sizes, int n_in,
                              void* d_out, int out_size, void* d_ws, size_t ws_size,
                              hipStream_t stream) {
    const float* x          = (const float*)d_in[0];
    const float* brightness = (const float*)d_in[1];
    const float* cfac       = (const float*)d_in[2];
    const int*   flip_mask  = (const int*)d_in[3];
    const int*   gray_mask  = (const int*)d_in[4];
    const int*   contrast_a = (const int*)d_in[5];
    float* out   = (float*)d_out;
    float* means = (float*)d_ws;  // 768 floats

    fusedA_kernel<<<NPLANES + B_ * BLOCKS_PER_IMG, BLK, 0, stream>>>(
        x, brightness, flip_mask, gray_mask, contrast_a, means, out);
    xformC_kernel<<<B_ * BLOCKS_PER_IMG, BLK, 0, stream>>>(
        x, brightness, cfac, flip_mask, gray_mask, contrast_a, means, out);
}